// Round 9
// baseline (4090.695 us; speedup 1.0000x reference)
//
#include <hip/hip_runtime.h>
#include <hip/hip_bf16.h>

#define B_   64
#define T_   512
#define DIN_ 256
#define H_   512

typedef __attribute__((ext_vector_type(2))) _Float16 h16x2;
typedef __attribute__((ext_vector_type(8))) _Float16 h16x8;
typedef __attribute__((ext_vector_type(2))) __fp16  fp16x2r;  // cvt_pkrtz return type
typedef __attribute__((ext_vector_type(4))) float f32x4;
typedef unsigned short u16;
typedef unsigned long long u64;

#define TSTRIDE 520   // staged-tile row stride in u16: 16B-aligned, <=4-way LDS conflicts

__device__ __forceinline__ float sigmf(float xv) {
  return 1.0f / (1.0f + __expf(-xv));
}

// ---- intra-XCD (L2-coherent) primitives (R6-proven) ----
__device__ __forceinline__ unsigned ld_flag_l2(const unsigned* p) {
  unsigned v;
  asm volatile("global_load_dword %0, %1, off sc0\n\ts_waitcnt vmcnt(0)"
               : "=v"(v) : "v"(p) : "memory");
  return v;
}
__device__ __forceinline__ void st_flag_l2(unsigned* p, unsigned v) {
  asm volatile("global_store_dword %0, %1, off sc0" :: "v"(p), "v"(v) : "memory");
}
#define LD16SC0(dst, p) \
  asm volatile("global_load_dwordx4 %0, %1, off sc0" : "=v"(dst) : "v"(p))
__device__ __forceinline__ void waitall4(h16x8* f) {
  asm volatile("s_waitcnt vmcnt(0)"
    : "+v"(f[0]), "+v"(f[1]), "+v"(f[2]), "+v"(f[3]) :: "memory");
}

// Poll 32 per-WG flags (one domain-step): lanes 0..31, distinct words, L2-hit.
__device__ __forceinline__ void waitL2(const unsigned* f, int lane) {
  int guard = 0;
  for (;;) {
    unsigned v = (lane < 32) ? ld_flag_l2(f + lane) : 1u;
    if (__all(v != 0u)) break;
    if (++guard > (1 << 20)) break;   // safety valve
  }
}
// Cross-XCD poll (agent scope, MALL) — only on the slack-buffered edges.
__device__ __forceinline__ void waitXC(const unsigned* f, int lane) {
  int guard = 0;
  for (;;) {
    unsigned v = (lane < 32)
      ? __hip_atomic_load((unsigned*)(f + lane), __ATOMIC_RELAXED, __HIP_MEMORY_SCOPE_AGENT)
      : 1u;
    if (__all(v != 0u)) break;
    if (++guard > (1 << 20)) break;
    __builtin_amdgcn_s_sleep(1);
  }
}
// Cross-XCD 16B ring read (agent, MALL-coherent; proven R4-R6 path).
__device__ __forceinline__ h16x8 ldring(const u16* p) {
  union { h16x8 h; u64 q[2]; } u;
  u.q[0] = __hip_atomic_load((u64*)p,       __ATOMIC_RELAXED, __HIP_MEMORY_SCOPE_AGENT);
  u.q[1] = __hip_atomic_load((u64*)(p + 4), __ATOMIC_RELAXED, __HIP_MEMORY_SCOPE_AGENT);
  return u.h;
}

__device__ __forceinline__ h16x8 pk8(f32x4 a, f32x4 b) {
  union { h16x8 h; fp16x2r p[4]; } u;
  u.p[0] = __builtin_amdgcn_cvt_pkrtz(a.x, a.y);
  u.p[1] = __builtin_amdgcn_cvt_pkrtz(a.z, a.w);
  u.p[2] = __builtin_amdgcn_cvt_pkrtz(b.x, b.y);
  u.p[3] = __builtin_amdgcn_cvt_pkrtz(b.z, b.w);
  return u.h;
}

// ---- R9: LDS broadcast staging. Each WG reads the 16x512 u16 h-tile ONCE
// (256 thr x 64B), not once per wave (R6's 128x duplication = 2MB/domain/step
// of MALL reads was the real cost). thread -> (row=tid&15, colblk=tid>>4). ----
__device__ __forceinline__ void stage_intra(const u16* src, u16* dst, int tid) {
  const int row = tid & 15, cb = tid >> 4;
  const u16* s = src + row * 512 + cb * 32;
  u16* d = dst + row * TSTRIDE + cb * 32;
  h16x8 v[4];
  LD16SC0(v[0], s);      LD16SC0(v[1], s + 8);
  LD16SC0(v[2], s + 16); LD16SC0(v[3], s + 24);
  waitall4(v);
  *(h16x8*)(d)      = v[0]; *(h16x8*)(d + 8)  = v[1];
  *(h16x8*)(d + 16) = v[2]; *(h16x8*)(d + 24) = v[3];
}
__device__ __forceinline__ void stage_cross(const u16* src, u16* dst, int tid) {
  const int row = tid & 15, cb = tid >> 4;
  const u16* s = src + row * 512 + cb * 32;
  u16* d = dst + row * TSTRIDE + cb * 32;
  h16x8 v0 = ldring(s), v1 = ldring(s + 8), v2 = ldring(s + 16), v3 = ldring(s + 24);
  *(h16x8*)(d)      = v0; *(h16x8*)(d + 8)  = v1;
  *(h16x8*)(d + 16) = v2; *(h16x8*)(d + 24) = v3;
}

// R9 = R6's proven flag protocol (per-WG sc0 flags + barrier + deferred cross
// flag) + LDS tile staging. Domain (LAYER, g) = 32 WGs on one XCD (claimed
// via XCC_ID). Intra: plain stores -> XCD L2, sc0 staged reads. Cross: agent
// atomics -> MALL, staged reads. Weights: LDS once -> VGPR B-frags; the LDS
// region is then reused for tile buffers (barrier after preload makes the
// WAR cross-wave hazard safe).
template <int LAYER>
__device__ __forceinline__ void lstm_body(
    const float* __restrict__ xin,
    const float* __restrict__ Wih, const float* __restrict__ Whh,
    const float* __restrict__ bih, const float* __restrict__ bhh,
    float* __restrict__ out,
    unsigned* __restrict__ iflags, unsigned* __restrict__ cf0,
    unsigned* __restrict__ cf1,
    u16* __restrict__ h0i, u16* __restrict__ h1i, u16* __restrict__ h0x,
    char* smem, int g, int j0, int slotW)
{
  constexpr int K    = LAYER ? 1024 : 768;
  constexpr int KP   = K + 8;
  constexpr int KIH  = LAYER ? 512 : 256;
  constexpr int NKB1 = KIH / 32;
  const int tid = threadIdx.x;
  _Float16* wlds = (_Float16*)smem;

  // ---- one-time: stage W slice (64 gate-rows x K) f32 -> fp16 LDS ----
  {
    const int c = tid;
    if (c < (K >> 2)) {
      for (int rho = 0; rho < 64; ++rho) {
        const int gI = rho & 3, jI = (rho >> 2) & 3, nt = rho >> 4;
        const int gr = gI * H_ + j0 + nt * 4 + jI;
        f32x4 v;
        if (c < (KIH >> 2))
          v = *(const f32x4*)(Wih + (size_t)gr * KIH + (size_t)c * 4);
        else
          v = *(const f32x4*)(Whh + (size_t)gr * H_ + (size_t)(c - (KIH >> 2)) * 4);
        h16x2 q0, q1;
        q0[0] = (_Float16)v.x; q0[1] = (_Float16)v.y;
        q1[0] = (_Float16)v.z; q1[1] = (_Float16)v.w;
        *(h16x2*)(wlds + rho * KP + c * 4)     = q0;
        *(h16x2*)(wlds + rho * KP + c * 4 + 2) = q1;
      }
    }
  }

  const int lane = tid & 63;
  const int w    = tid >> 6;
  const int n    = lane & 15;
  const int quad = lane >> 4;
  const int gI   = n & 3;
  const int jI   = n >> 2;
  const int jglob = j0 + w * 4 + jI;
  const float bias = bih[gI * H_ + jglob] + bhh[gI * H_ + jglob];
  const int koffA = quad * 8;
  const _Float16* bbase = wlds + (w * 16 + n) * KP + koffA;

  __syncthreads();   // weight staging complete

  // preload weight B-frags into VGPRs (no per-step LDS weight traffic)
  h16x8 bA[NKB1], bB[16];
#pragma unroll
  for (int kb = 0; kb < NKB1; ++kb) bA[kb] = *(const h16x8*)(bbase + kb * 32);
#pragma unroll
  for (int kb = 0; kb < 16; ++kb)   bB[kb] = *(const h16x8*)(bbase + KIH + kb * 32);

  __syncthreads();   // ALL waves done reading weights -> LDS reusable for tiles

  u16* tile0 = (u16*)smem;                       // h[t-1] intra tile (16xTSTRIDE)
  u16* tile1 = (u16*)smem + 16 * TSTRIDE;        // h0[t] cross tile (L1 only)

  unsigned* ifl  = iflags + (size_t)(LAYER * 4 + g) * T_ * 32;  // intra per-WG flags
  unsigned* cf0g = cf0 + (size_t)g * T_ * 32;                   // cross L0-done
  unsigned* cf1g = cf1 + (size_t)g * T_ * 32;                   // cross L1-consumed
  u16* myIr = (LAYER ? h1i : h0i) + (size_t)g * 65536;          // [8][16][512] u16
  u16* h0xg = h0x + (size_t)g * 65536;

  f32x4 cst = {0.f, 0.f, 0.f, 0.f};

  for (int t = 0; t < T_; ++t) {
    f32x4 acc  = {0.f, 0.f, 0.f, 0.f};
    f32x4 acc2 = {0.f, 0.f, 0.f, 0.f};

    if (LAYER == 0) {
      // part 1: W_ih * x_t — immutable global, no deps, overlaps peer skew
      const float* a0 = xin + (size_t)(g * 16 + n) * (T_ * DIN_) + (size_t)t * DIN_ + koffA;
#pragma unroll
      for (int kb = 0; kb < NKB1; ++kb) {
        h16x8 af = pk8(*(const f32x4*)(a0 + kb * 32), *(const f32x4*)(a0 + kb * 32 + 4));
        acc = __builtin_amdgcn_mfma_f32_16x16x32_f16(af, bA[kb], acc, 0, 0, 0);
      }
      if (t > 0) {
        waitL2(ifl + (size_t)(t - 1) * 32, lane);
        stage_intra(myIr + (size_t)((t - 1) & 7) * 8192, tile0, tid);
        __syncthreads();   // tile staged by all threads
        const _Float16* tp = (const _Float16*)tile0 + n * TSTRIDE + koffA;
#pragma unroll
        for (int kb = 0; kb < 16; ++kb)
          acc2 = __builtin_amdgcn_mfma_f32_16x16x32_f16(*(const h16x8*)(tp + kb * 32),
                                                        bB[kb], acc2, 0, 0, 0);
      }
      // cross backpressure (slot t&7 reuse); pre-satisfied in steady state
      if (t >= 8) waitXC(cf1g + (size_t)(t - 8) * 32, lane);
    } else {
      // cross edge: pre-satisfied wait (L0 ~8 ahead), stage h0[t] from MALL
      waitXC(cf0g + (size_t)t * 32, lane);
      stage_cross(h0xg + (size_t)(t & 7) * 8192, tile1, tid);
      if (t > 0) {
        waitL2(ifl + (size_t)(t - 1) * 32, lane);
        stage_intra(myIr + (size_t)((t - 1) & 7) * 8192, tile0, tid);
      }
      __syncthreads();   // both tiles staged
      if (t > 0) {
        const _Float16* tp = (const _Float16*)tile0 + n * TSTRIDE + koffA;
#pragma unroll
        for (int kb = 0; kb < 16; ++kb)
          acc2 = __builtin_amdgcn_mfma_f32_16x16x32_f16(*(const h16x8*)(tp + kb * 32),
                                                        bB[kb], acc2, 0, 0, 0);
      }
      const _Float16* xp = (const _Float16*)tile1 + n * TSTRIDE + koffA;
#pragma unroll
      for (int kb = 0; kb < 16; ++kb)
        acc = __builtin_amdgcn_mfma_f32_16x16x32_f16(*(const h16x8*)(xp + kb * 32),
                                                     bA[kb], acc, 0, 0, 0);
    }

    // ---- elementwise (batched shfl -> batched transcendental) ----
    float pre[4], vi[4], vf[4], vg[4], vo[4], hv[4];
#pragma unroll
    for (int r = 0; r < 4; ++r) pre[r] = acc[r] + acc2[r] + bias;
#pragma unroll
    for (int r = 0; r < 4; ++r) {
      vi[r] = __shfl(pre[r], 0, 4);   // quad lanes hold i,f,g,o of one unit
      vf[r] = __shfl(pre[r], 1, 4);
      vg[r] = __shfl(pre[r], 2, 4);
      vo[r] = __shfl(pre[r], 3, 4);
    }
#pragma unroll
    for (int r = 0; r < 4; ++r) {
      float tg  = 2.f * sigmf(2.f * vg[r]) - 1.f;
      float cnv = sigmf(vf[r]) * cst[r] + sigmf(vi[r]) * tg;
      cst[r] = cnv;
      hv[r] = sigmf(vo[r]) * (2.f * sigmf(2.f * cnv) - 1.f);
    }

    u16* ringW = myIr + (size_t)(t & 7) * 8192;
    const bool act = ((lane & 7) == 0);
    const bool lastT = (t == T_ - 1);
    unsigned sv[4];
#pragma unroll
    for (int r = 0; r < 4; ++r) {
      float hv2 = __shfl(hv[r], lane + 4);      // partner column (n+4)
      if (act) {
        _Float16 ha = (_Float16)hv[r], hb2 = (_Float16)hv2;   // RTN (R6 numerics)
        union { struct { u16 a, b; } s; unsigned u; } pku;
        pku.s.a = *(const u16*)&ha; pku.s.b = *(const u16*)&hb2;
        sv[r] = pku.u;
        // intra ring: plain store (write-through to XCD L2); fire-and-forget
        *(unsigned*)&ringW[(size_t)(quad * 4 + r) * 512 + jglob] = sv[r];
      }
      if (lastT && (lane & 3) == 0) {
        const int gb = g * 16 + quad * 4 + r;
        out[64 + LAYER * (B_ * H_) + gb * H_ + jglob] = hv[r];                  // hn
        out[64 + 2 * (B_ * H_) + LAYER * (B_ * H_) + gb * H_ + jglob] = cst[r]; // cn
      }
    }

    // ---- publish: drain intra stores (L2 ack; prior-step cross stores long
    // acked), barrier, per-WG flags. cf0 deferred 1 step (MALL ack off the
    // critical path); cf1 = consumption progress, publish immediately. ----
    asm volatile("s_waitcnt vmcnt(0)" ::: "memory");
    __syncthreads();
    if (tid == 0) {
      st_flag_l2(ifl + (size_t)t * 32 + slotW, 1u);
      if (LAYER == 0) {
        if (t > 0)
          __hip_atomic_store(cf0g + (size_t)(t - 1) * 32 + slotW, 1u,
                             __ATOMIC_RELAXED, __HIP_MEMORY_SCOPE_AGENT);
      } else {
        __hip_atomic_store(cf1g + (size_t)t * 32 + slotW, 1u,
                           __ATOMIC_RELAXED, __HIP_MEMORY_SCOPE_AGENT);
      }
    }
    // cross-ring stores of h0[t] (L0 only), fire-and-forget; acked during the
    // next step, published with cf0[t] one step later
    if (LAYER == 0 && act) {
      u16* xw = h0xg + (size_t)(t & 7) * 8192;
#pragma unroll
      for (int r = 0; r < 4; ++r)
        __hip_atomic_store((unsigned*)&xw[(size_t)(quad * 4 + r) * 512 + jglob], sv[r],
                           __ATOMIC_RELAXED, __HIP_MEMORY_SCOPE_AGENT);
    }
  }

  // final cross flag for t = T-1 (loop defers cf0 by one step)
  if (LAYER == 0) {
    asm volatile("s_waitcnt vmcnt(0)" ::: "memory");
    __syncthreads();
    if (tid == 0)
      __hip_atomic_store(cf0g + (size_t)(T_ - 1) * 32 + slotW, 1u,
                         __ATOMIC_RELAXED, __HIP_MEMORY_SCOPE_AGENT);
  }
}

__global__ void __launch_bounds__(256, 1) lstm_kernel(
    const float* x,
    const float* Wih0, const float* Whh0, const float* bih0, const float* bhh0,
    const float* Wih1, const float* Whh1, const float* bih1, const float* bhh1,
    float* out, unsigned* claim, unsigned* iflags, unsigned* cf0, unsigned* cf1,
    u16* h0i, u16* h1i, u16* h0x)
{
  __shared__ unsigned role[2];
  extern __shared__ char smem[];
  if (threadIdx.x == 0) {
    // physical XCD id (HW_REG_XCC_ID = 20); claim a role slot on THIS XCD
    unsigned xcc = __builtin_amdgcn_s_getreg((31 << 11) | 20) & 7u;
    unsigned slot = __hip_atomic_fetch_add(&claim[xcc], 1u,
                                           __ATOMIC_RELAXED, __HIP_MEMORY_SCOPE_AGENT);
    role[0] = xcc; role[1] = slot & 31u;
  }
  __syncthreads();
  const int xcc = role[0], slotW = role[1];
  const int layer = xcc & 1, g = (xcc >> 1) & 3, j0 = slotW * 16;
  if (layer == 0)
    lstm_body<0>(x, Wih0, Whh0, bih0, bhh0, out, iflags, cf0, cf1,
                 h0i, h1i, h0x, smem, g, j0, slotW);
  else
    lstm_body<1>(x, Wih1, Whh1, bih1, bhh1, out, iflags, cf0, cf1,
                 h0i, h1i, h0x, smem, g, j0, slotW);
}

__global__ void init_kernel(unsigned* p, int nw) {
  int i = blockIdx.x * blockDim.x + threadIdx.x;
  for (; i < nw; i += gridDim.x * blockDim.x) p[i] = 0;
}

__global__ void fc_kernel(const float* __restrict__ hn1,
                          const float* __restrict__ fcw,
                          const float* __restrict__ fcb,
                          float* __restrict__ out) {
  const int tid = threadIdx.x;
  const int b = tid >> 2, q = tid & 3;
  const float* hr = hn1 + b * H_ + q * 128;
  const float* wr = fcw + q * 128;
  float s = 0.f;
  for (int i = 0; i < 128; ++i) s += hr[i] * wr[i];
  s += __shfl_xor(s, 1, 4);
  s += __shfl_xor(s, 2, 4);
  if (q == 0) out[b] = s + fcb[0];
}

extern "C" void kernel_launch(void* const* d_in, const int* in_sizes, int n_in,
                              void* d_out, int out_size, void* d_ws, size_t ws_size,
                              hipStream_t stream) {
  const float* x    = (const float*)d_in[0];
  const float* Wih0 = (const float*)d_in[1];
  const float* Whh0 = (const float*)d_in[2];
  const float* bih0 = (const float*)d_in[3];
  const float* bhh0 = (const float*)d_in[4];
  const float* Wih1 = (const float*)d_in[5];
  const float* Whh1 = (const float*)d_in[6];
  const float* bih1 = (const float*)d_in[7];
  const float* bhh1 = (const float*)d_in[8];
  const float* fcw  = (const float*)d_in[9];
  const float* fcb  = (const float*)d_in[10];
  float* out = (float*)d_out;

  // ws layout (bytes): claim[256w]@0 | iflags[2*4*512*32w]@1024 |
  // cf0[4*512*32w]@525312 | cf1@787456 | h0i[4][8][16][512]u16@1049600 |
  // h1i@1573888 | h0x@2098176 | end 2622464
  unsigned* claim  = (unsigned*)d_ws;
  unsigned* iflags = (unsigned*)((char*)d_ws + 1024);
  unsigned* cf0    = (unsigned*)((char*)d_ws + 525312);
  unsigned* cf1    = (unsigned*)((char*)d_ws + 787456);
  u16* h0i = (u16*)((char*)d_ws + 1049600);
  u16* h1i = (u16*)((char*)d_ws + 1573888);
  u16* h0x = (u16*)((char*)d_ws + 2098176);

  init_kernel<<<256, 256, 0, stream>>>(claim, 262400);  // claim + all flags

  const int ldsBytes = 64 * (1024 + 8) * 2;  // 132096 B -> forces 1 WG/CU
  (void)hipFuncSetAttribute((const void*)lstm_kernel,
                            hipFuncAttributeMaxDynamicSharedMemorySize, ldsBytes);
  // grid 256 == CU count: with 1 WG/CU, every XCD hosts exactly 32 WGs
  lstm_kernel<<<256, 256, ldsBytes, stream>>>(x, Wih0, Whh0, bih0, bhh0,
                                              Wih1, Whh1, bih1, bhh1,
                                              out, claim, iflags, cf0, cf1,
                                              h0i, h1i, h0x);
  fc_kernel<<<1, 256, 0, stream>>>(out + 64 + B_ * H_, fcw, fcb, out);
}